// Round 1
// baseline (2633.304 us; speedup 1.0000x reference)
//
#include <hip/hip_runtime.h>

// LRU forward: y = Re(scan(lam, gamma*(x@B^T)) @ C^T) + x @ D^T
// Shapes: x[8,4096,1024], B[512,1024] (re,im), C[1024,512] (re,im), D[1024,1024]
// fp32 baseline round: vector-FMA tiled GEMMs + 2-level chunked scan.

#define BSZ   8
#define TLEN  4096
#define DIN   1024
#define DOUT  1024
#define NST   512
#define M_TOT (BSZ * TLEN)   // 32768
#define NC    32             // scan chunks per sequence
#define CL    128            // chunk length; NC*CL == TLEN

#define BM  128
#define BN  128
#define BK  16
#define LDT 132              // LDS leading dim: 132*4B = 528 = 16*33 -> float4-aligned rows

// ---------------- shared tiled-GEMM phase: acc += A[m0+..][K] * B[n0+..][K]^T (NT) ---------
__device__ __forceinline__ void gphase(
    const float* __restrict__ A, const float* __restrict__ Bm, const int K, const float sgn,
    float (&acc)[8][8], float (*__restrict__ As)[LDT], float (*__restrict__ Bs)[LDT],
    const int m0, const int n0, const int tid)
{
  const int row  = tid >> 1;   // 0..127
  const int half = tid & 1;    // which 8 of the 16 k's this thread stages
  const int ty   = tid >> 4;   // 0..15
  const int tx   = tid & 15;   // 0..15

  const float* pa = A  + (size_t)(m0 + row) * K + half * 8;
  const float* pb = Bm + (size_t)(n0 + row) * K + half * 8;

  float4 a0 = *(const float4*)(pa);
  float4 a1 = *(const float4*)(pa + 4);
  float4 b0 = *(const float4*)(pb);
  float4 b1 = *(const float4*)(pb + 4);

  for (int k0 = 0; k0 < K; k0 += BK) {
    __syncthreads();   // previous tile's reads done before overwrite
    {
      const int kb = half * 8;
      As[kb+0][row] = a0.x; As[kb+1][row] = a0.y; As[kb+2][row] = a0.z; As[kb+3][row] = a0.w;
      As[kb+4][row] = a1.x; As[kb+5][row] = a1.y; As[kb+6][row] = a1.z; As[kb+7][row] = a1.w;
      Bs[kb+0][row] = sgn*b0.x; Bs[kb+1][row] = sgn*b0.y; Bs[kb+2][row] = sgn*b0.z; Bs[kb+3][row] = sgn*b0.w;
      Bs[kb+4][row] = sgn*b1.x; Bs[kb+5][row] = sgn*b1.y; Bs[kb+6][row] = sgn*b1.z; Bs[kb+7][row] = sgn*b1.w;
    }
    __syncthreads();
    if (k0 + BK < K) {         // prefetch next tile, overlapped with compute below
      pa += BK; pb += BK;
      a0 = *(const float4*)(pa); a1 = *(const float4*)(pa + 4);
      b0 = *(const float4*)(pb); b1 = *(const float4*)(pb + 4);
    }
    #pragma unroll
    for (int kk = 0; kk < BK; ++kk) {
      const float4 al = *(const float4*)&As[kk][ty*4];
      const float4 ah = *(const float4*)&As[kk][64 + ty*4];
      const float4 bl = *(const float4*)&Bs[kk][tx*4];
      const float4 bh = *(const float4*)&Bs[kk][64 + tx*4];
      const float av[8] = {al.x,al.y,al.z,al.w, ah.x,ah.y,ah.z,ah.w};
      const float bv[8] = {bl.x,bl.y,bl.z,bl.w, bh.x,bh.y,bh.z,bh.w};
      #pragma unroll
      for (int i = 0; i < 8; ++i)
        #pragma unroll
        for (int j = 0; j < 8; ++j)
          acc[i][j] = fmaf(av[i], bv[j], acc[i][j]);
    }
  }
}

// ---------------- kernel 1: Bu (re & im planes) = gamma * (x @ [Bre;Bim]^T) ----------------
__global__ __launch_bounds__(256) void bu_gemm(
    const float* __restrict__ x, const float* __restrict__ Bre, const float* __restrict__ Bim,
    const float* __restrict__ gamma, float* __restrict__ bure, float* __restrict__ buim)
{
  __shared__ float As[BK][LDT];
  __shared__ float Bs[BK][LDT];
  float acc[8][8] = {};
  const int tid = threadIdx.x;
  const int m0  = blockIdx.x * BM;
  const int n0s = blockIdx.y * BN;              // stacked col index 0..1023
  const float* Bsrc = (n0s < NST) ? Bre : Bim;  // tiles never straddle the 512 boundary
  const int nb = n0s & (NST - 1);

  gphase(x, Bsrc, DIN, 1.0f, acc, As, Bs, m0, nb, tid);

  float* outp = (n0s < NST) ? bure : buim;
  const int ty = tid >> 4, tx = tid & 15;
  const float4 g0 = *(const float4*)&gamma[nb + tx*4];
  const float4 g1 = *(const float4*)&gamma[nb + 64 + tx*4];
  const float gv[8] = {g0.x,g0.y,g0.z,g0.w, g1.x,g1.y,g1.z,g1.w};
  #pragma unroll
  for (int ih = 0; ih < 2; ++ih)
  #pragma unroll
  for (int i = 0; i < 4; ++i) {
    const size_t m = (size_t)m0 + ih*64 + ty*4 + i;
    #pragma unroll
    for (int jh = 0; jh < 2; ++jh) {
      float4 v;
      v.x = acc[ih*4+i][jh*4+0] * gv[jh*4+0];
      v.y = acc[ih*4+i][jh*4+1] * gv[jh*4+1];
      v.z = acc[ih*4+i][jh*4+2] * gv[jh*4+2];
      v.w = acc[ih*4+i][jh*4+3] * gv[jh*4+3];
      *(float4*)&outp[m * NST + nb + jh*64 + tx*4] = v;
    }
  }
}

// ---------------- scan param precompute -----------------------------------------------------
__global__ void params_k(const float* __restrict__ nulog, const float* __restrict__ thlog,
                         const float* __restrict__ glog,
                         float2* __restrict__ lam, float2* __restrict__ lamL,
                         float* __restrict__ gamma)
{
  const int n = blockIdx.x * 256 + threadIdx.x;
  if (n >= NST) return;
  const float nu = expf(nulog[n]);
  const float th = expf(thlog[n]);
  const float mod = expf(-nu);
  float s, c;
  sincosf(th, &s, &c);
  lam[n] = make_float2(mod * c, mod * s);
  const float modL = expf(-(float)CL * nu);
  float sL, cL;
  sincosf((float)CL * th, &sL, &cL);
  lamL[n] = make_float2(modL * cL, modL * sL);
  gamma[n] = expf(glog[n]);
}

// ---------------- scan phase 1: per-chunk local scan (zero init), emit chunk-final ---------
__global__ __launch_bounds__(256) void scan_partial(
    const float* __restrict__ bure, const float* __restrict__ buim,
    const float2* __restrict__ lam, float2* __restrict__ carry)
{
  const int g = blockIdx.x * 256 + threadIdx.x;   // 8*32*512 = 131072 threads
  const int n = g & (NST - 1);
  const int c = (g >> 9) & (NC - 1);
  const int b = g >> 14;
  const float2 L = lam[n];
  const size_t base = ((size_t)b * TLEN + (size_t)c * CL) * NST + n;
  float sr = 0.f, si = 0.f;
  #pragma unroll 8
  for (int t = 0; t < CL; ++t) {
    const float br = bure[base + (size_t)t * NST];
    const float bi = buim[base + (size_t)t * NST];
    const float nr = fmaf(L.x, sr, fmaf(-L.y, si, br));
    const float ni = fmaf(L.x, si, fmaf( L.y, sr, bi));
    sr = nr; si = ni;
  }
  carry[(size_t)(b * NC + c) * NST + n] = make_float2(sr, si);
}

// ---------------- scan phase 2: scan the 32 chunk summaries per (b,n), in place ------------
__global__ __launch_bounds__(256) void scan_carry(
    float2* __restrict__ carry, const float2* __restrict__ lamL)
{
  const int g = blockIdx.x * 256 + threadIdx.x;   // 8*512 = 4096 threads
  const int n = g & (NST - 1);
  const int b = g >> 9;
  const float2 P = lamL[n];
  float sr = 0.f, si = 0.f;
  for (int c = 0; c < NC; ++c) {
    const size_t idx = (size_t)(b * NC + c) * NST + n;
    const float2 v = carry[idx];
    carry[idx] = make_float2(sr, si);             // carry-IN for chunk c
    const float nr = fmaf(P.x, sr, fmaf(-P.y, si, v.x));
    const float ni = fmaf(P.x, si, fmaf( P.y, sr, v.y));
    sr = nr; si = ni;
  }
}

// ---------------- scan phase 3: re-scan with carry-in, write states in place over Bu -------
__global__ __launch_bounds__(256) void scan_final(
    float* __restrict__ bure, float* __restrict__ buim,
    const float2* __restrict__ lam, const float2* __restrict__ carry)
{
  const int g = blockIdx.x * 256 + threadIdx.x;
  const int n = g & (NST - 1);
  const int c = (g >> 9) & (NC - 1);
  const int b = g >> 14;
  const float2 L = lam[n];
  const float2 ci = carry[(size_t)(b * NC + c) * NST + n];
  const size_t base = ((size_t)b * TLEN + (size_t)c * CL) * NST + n;
  float sr = ci.x, si = ci.y;
  #pragma unroll 8
  for (int t = 0; t < CL; ++t) {
    const size_t idx = base + (size_t)t * NST;
    const float br = bure[idx];
    const float bi = buim[idx];
    const float nr = fmaf(L.x, sr, fmaf(-L.y, si, br));
    const float ni = fmaf(L.x, si, fmaf( L.y, sr, bi));
    sr = nr; si = ni;
    bure[idx] = sr;
    buim[idx] = si;
  }
}

// ---------------- kernel 5: y = st_re@Cre^T - st_im@Cim^T + x@D^T --------------------------
__global__ __launch_bounds__(256) void out_gemm(
    const float* __restrict__ stre, const float* __restrict__ stim,
    const float* __restrict__ x,
    const float* __restrict__ Cre, const float* __restrict__ Cim,
    const float* __restrict__ Dm, float* __restrict__ y)
{
  __shared__ float As[BK][LDT];
  __shared__ float Bs[BK][LDT];
  float acc[8][8] = {};
  const int tid = threadIdx.x;
  const int m0 = blockIdx.x * BM;
  const int o0 = blockIdx.y * BN;

  gphase(stre, Cre, NST, 1.0f, acc, As, Bs, m0, o0, tid);
  gphase(stim, Cim, NST, -1.0f, acc, As, Bs, m0, o0, tid);
  gphase(x,    Dm,  DIN, 1.0f, acc, As, Bs, m0, o0, tid);

  const int ty = tid >> 4, tx = tid & 15;
  #pragma unroll
  for (int ih = 0; ih < 2; ++ih)
  #pragma unroll
  for (int i = 0; i < 4; ++i) {
    const size_t m = (size_t)m0 + ih*64 + ty*4 + i;
    #pragma unroll
    for (int jh = 0; jh < 2; ++jh) {
      float4 v;
      v.x = acc[ih*4+i][jh*4+0];
      v.y = acc[ih*4+i][jh*4+1];
      v.z = acc[ih*4+i][jh*4+2];
      v.w = acc[ih*4+i][jh*4+3];
      *(float4*)&y[m * DOUT + o0 + jh*64 + tx*4] = v;
    }
  }
}

// ---------------- host launch ---------------------------------------------------------------
extern "C" void kernel_launch(void* const* d_in, const int* in_sizes, int n_in,
                              void* d_out, int out_size, void* d_ws, size_t ws_size,
                              hipStream_t stream)
{
  (void)in_sizes; (void)n_in; (void)out_size; (void)ws_size;
  const float* x     = (const float*)d_in[0];
  const float* nulog = (const float*)d_in[1];
  const float* thlog = (const float*)d_in[2];
  const float* glog  = (const float*)d_in[3];
  const float* Bre   = (const float*)d_in[4];
  const float* Bim   = (const float*)d_in[5];
  const float* Cre   = (const float*)d_in[6];
  const float* Cim   = (const float*)d_in[7];
  const float* Dm    = (const float*)d_in[8];
  float* y = (float*)d_out;

  // workspace layout (~129.3 MB): bure | buim | carry | lam | lamL | gamma
  float*  bure  = (float*)d_ws;
  float*  buim  = bure + (size_t)M_TOT * NST;
  float2* carry = (float2*)(buim + (size_t)M_TOT * NST);
  float2* lam   = carry + (size_t)BSZ * NC * NST;
  float2* lamL  = lam + NST;
  float*  gamma = (float*)(lamL + NST);

  params_k<<<2, 256, 0, stream>>>(nulog, thlog, glog, lam, lamL, gamma);
  bu_gemm<<<dim3(M_TOT / BM, (2 * NST) / BN), 256, 0, stream>>>(x, Bre, Bim, gamma, bure, buim);
  scan_partial<<<(BSZ * NC * NST) / 256, 256, 0, stream>>>(bure, buim, lam, carry);
  scan_carry<<<(BSZ * NST) / 256, 256, 0, stream>>>(carry, lamL);
  scan_final<<<(BSZ * NC * NST) / 256, 256, 0, stream>>>(bure, buim, lam, carry);
  out_gemm<<<dim3(M_TOT / BM, DOUT / BN), 256, 0, stream>>>(bure, buim, x, Cre, Cim, Dm, y);
}

// Round 2
// 1040.135 us; speedup vs baseline: 2.5317x; 2.5317x over previous
//
#include <hip/hip_runtime.h>

// LRU forward: y = Re(scan(lam, gamma*(x@B^T)) @ C^T) + x @ D^T
// Round 2: bf16x3 split-precision MFMA GEMMs (Ah*Bh + Ah*Bl + Al*Bh, fp32 acc),
// 128x128 tile / BK=32 / 4 waves / 16x16x32 MFMA, reg-staged conversion (ws-safe).
// Bu/states stored as 4 bf16 hi/lo planes in workspace (same bytes as fp32 re/im).

#define BSZ   8
#define TLEN  4096
#define DIN   1024
#define DOUT  1024
#define NST   512
#define M_TOT (BSZ * TLEN)   // 32768
#define NC    32             // scan chunks per sequence
#define CL    128            // chunk length; NC*CL == TLEN

typedef __attribute__((ext_vector_type(8))) short bf16x8;   // MFMA A/B frag (4 VGPR)
typedef __attribute__((ext_vector_type(4))) float f32x4;    // MFMA C/D frag

// ---- bf16 helpers (bit-level, RNE) --------------------------------------------------------
__device__ __forceinline__ float s2f(short s) {
  unsigned v = ((unsigned)(unsigned short)s) << 16;
  return __builtin_bit_cast(float, v);
}
__device__ __forceinline__ short f2s(float f) {
  unsigned u = __builtin_bit_cast(unsigned, f);
  unsigned r = (u + 0x7FFFu + ((u >> 16) & 1u)) >> 16;
  return (short)r;
}
__device__ __forceinline__ void split(float f, short& h, short& l) {
  h = f2s(f);
  l = f2s(f - s2f(h));
}
__device__ __forceinline__ void split8(const float4 v0, const float4 v1, const float sgn,
                                       bf16x8& hv, bf16x8& lv) {
  const float f[8] = {v0.x, v0.y, v0.z, v0.w, v1.x, v1.y, v1.z, v1.w};
  #pragma unroll
  for (int j = 0; j < 8; ++j) { short hh, ll; split(sgn * f[j], hh, ll); hv[j] = hh; lv[j] = ll; }
}

// ---- MFMA compute for one staged K-step (BK=32) -------------------------------------------
__device__ __forceinline__ void mma_step(f32x4 (&acc)[4][4],
    const short* __restrict__ Ah, const short* __restrict__ Al,
    const short* __restrict__ Bh, const short* __restrict__ Bl,
    const int wm, const int wn, const int lane)
{
  const int lr = lane & 15, kg = lane >> 4;
  bf16x8 ah[4], al[4];
  #pragma unroll
  for (int mi = 0; mi < 4; ++mi) {
    const int ro = (wm * 64 + mi * 16 + lr) * 32 + kg * 8;
    ah[mi] = *(const bf16x8*)&Ah[ro];
    al[mi] = *(const bf16x8*)&Al[ro];
  }
  #pragma unroll
  for (int ni = 0; ni < 4; ++ni) {
    const int co = (wn * 64 + ni * 16 + lr) * 32 + kg * 8;
    const bf16x8 bh = *(const bf16x8*)&Bh[co];
    const bf16x8 bl = *(const bf16x8*)&Bl[co];
    #pragma unroll
    for (int mi = 0; mi < 4; ++mi) {
      acc[mi][ni] = __builtin_amdgcn_mfma_f32_16x16x32_bf16(ah[mi], bh, acc[mi][ni], 0, 0, 0);
      acc[mi][ni] = __builtin_amdgcn_mfma_f32_16x16x32_bf16(ah[mi], bl, acc[mi][ni], 0, 0, 0);
      acc[mi][ni] = __builtin_amdgcn_mfma_f32_16x16x32_bf16(al[mi], bh, acc[mi][ni], 0, 0, 0);
    }
  }
}

// ---- one GEMM phase: acc += Asrc[m0+..][K] * Bsrc[n0+..][K]^T (NT), split-bf16x3 ----------
// APLANES=1: A comes pre-split as two bf16 planes (row-major [*, lda]).
// APLANES=0: A is fp32, split on the fly. B is always fp32 (weights), sign folded in.
template<bool APLANES>
__device__ __forceinline__ void gemm_phase(
    const float* __restrict__ Af, const short* __restrict__ Aph, const short* __restrict__ Apl,
    const int lda,
    const float* __restrict__ Bf, const int ldb, const float bsgn,
    const int K, const int m0, const int n0, const int tid,
    f32x4 (&acc)[4][4], short* Ah, short* Al, short* Bh, short* Bl)
{
  const int r    = tid & 127;   // staged row (A: m-row, B: n-row)
  const int kh   = tid >> 7;    // which 16-wide half of the 32 k's
  const int lane = tid & 63, w = tid >> 6, wm = w >> 1, wn = w & 1;

  float4 pa[4], pb[4];
  bf16x8 ph0, ph1, pl0, pl1;

  if constexpr (APLANES) {
    const size_t off = (size_t)(m0 + r) * lda + kh * 16;
    ph0 = *(const bf16x8*)(Aph + off);  ph1 = *(const bf16x8*)(Aph + off + 8);
    pl0 = *(const bf16x8*)(Apl + off);  pl1 = *(const bf16x8*)(Apl + off + 8);
  } else {
    const float* p = Af + (size_t)(m0 + r) * lda + kh * 16;
    #pragma unroll
    for (int i = 0; i < 4; ++i) pa[i] = *(const float4*)(p + 4 * i);
  }
  {
    const float* p = Bf + (size_t)(n0 + r) * ldb + kh * 16;
    #pragma unroll
    for (int i = 0; i < 4; ++i) pb[i] = *(const float4*)(p + 4 * i);
  }

  for (int k0 = 0; k0 < K; k0 += 32) {
    __syncthreads();                       // prior K-step's LDS reads complete
    const int wo = r * 32 + kh * 16;
    if constexpr (APLANES) {
      *(bf16x8*)&Ah[wo] = ph0;  *(bf16x8*)&Ah[wo + 8] = ph1;
      *(bf16x8*)&Al[wo] = pl0;  *(bf16x8*)&Al[wo + 8] = pl1;
    } else {
      bf16x8 hv0, lv0, hv1, lv1;
      split8(pa[0], pa[1], 1.0f, hv0, lv0);
      split8(pa[2], pa[3], 1.0f, hv1, lv1);
      *(bf16x8*)&Ah[wo] = hv0;  *(bf16x8*)&Ah[wo + 8] = hv1;
      *(bf16x8*)&Al[wo] = lv0;  *(bf16x8*)&Al[wo + 8] = lv1;
    }
    {
      bf16x8 hv0, lv0, hv1, lv1;
      split8(pb[0], pb[1], bsgn, hv0, lv0);
      split8(pb[2], pb[3], bsgn, hv1, lv1);
      *(bf16x8*)&Bh[wo] = hv0;  *(bf16x8*)&Bh[wo + 8] = hv1;
      *(bf16x8*)&Bl[wo] = lv0;  *(bf16x8*)&Bl[wo + 8] = lv1;
    }
    __syncthreads();
    if (k0 + 32 < K) {                     // prefetch next K-tile, overlaps MFMA below
      if constexpr (APLANES) {
        const size_t off = (size_t)(m0 + r) * lda + (k0 + 32) + kh * 16;
        ph0 = *(const bf16x8*)(Aph + off);  ph1 = *(const bf16x8*)(Aph + off + 8);
        pl0 = *(const bf16x8*)(Apl + off);  pl1 = *(const bf16x8*)(Apl + off + 8);
      } else {
        const float* p = Af + (size_t)(m0 + r) * lda + (k0 + 32) + kh * 16;
        #pragma unroll
        for (int i = 0; i < 4; ++i) pa[i] = *(const float4*)(p + 4 * i);
      }
      const float* p = Bf + (size_t)(n0 + r) * ldb + (k0 + 32) + kh * 16;
      #pragma unroll
      for (int i = 0; i < 4; ++i) pb[i] = *(const float4*)(p + 4 * i);
    }
    mma_step(acc, Ah, Al, Bh, Bl, wm, wn, lane);
  }
}

// ---- kernel 1: Bu planes = split_bf16(gamma * (x @ [Bre|Bim]^T)) --------------------------
__global__ __launch_bounds__(256, 2) void bu_mfma(
    const float* __restrict__ x, const float* __restrict__ Bre, const float* __restrict__ Bim,
    const float* __restrict__ gamma,
    short* __restrict__ re_h, short* __restrict__ re_l,
    short* __restrict__ im_h, short* __restrict__ im_l)
{
  __shared__ short Ah[128 * 32], Al[128 * 32], Bh[128 * 32], Bl[128 * 32];
  f32x4 acc[4][4] = {};
  const int tid = threadIdx.x;
  const int m0  = blockIdx.x * 128;
  const int n0s = blockIdx.y * 128;                  // stacked col 0..1023
  const float* Bsel = (n0s < NST) ? Bre : Bim;
  const int nb0 = n0s & (NST - 1);

  gemm_phase<false>(x, nullptr, nullptr, DIN, Bsel, DIN, 1.0f, DIN, m0, nb0, tid,
                    acc, Ah, Al, Bh, Bl);

  short* Hp = (n0s < NST) ? re_h : im_h;
  short* Lp = (n0s < NST) ? re_l : im_l;
  const int lane = tid & 63, w = tid >> 6, wm = w >> 1, wn = w & 1;
  const int lr = lane & 15, lq = lane >> 4;
  #pragma unroll
  for (int ni = 0; ni < 4; ++ni) {
    const int nb = nb0 + wn * 64 + ni * 16 + lr;
    const float g = gamma[nb];
    #pragma unroll
    for (int mi = 0; mi < 4; ++mi)
      #pragma unroll
      for (int j = 0; j < 4; ++j) {
        const size_t m = (size_t)m0 + wm * 64 + mi * 16 + lq * 4 + j;
        short hh, ll;
        split(acc[mi][ni][j] * g, hh, ll);
        Hp[m * NST + nb] = hh;
        Lp[m * NST + nb] = ll;
      }
  }
}

// ---- scan params --------------------------------------------------------------------------
__global__ void params_k(const float* __restrict__ nulog, const float* __restrict__ thlog,
                         const float* __restrict__ glog,
                         float2* __restrict__ lam, float2* __restrict__ lamL,
                         float* __restrict__ gamma)
{
  const int n = blockIdx.x * 256 + threadIdx.x;
  if (n >= NST) return;
  const float nu = expf(nulog[n]);
  const float th = expf(thlog[n]);
  const float mod = expf(-nu);
  float s, c;
  sincosf(th, &s, &c);
  lam[n] = make_float2(mod * c, mod * s);
  const float modL = expf(-(float)CL * nu);
  float sL, cL;
  sincosf((float)CL * th, &sL, &cL);
  lamL[n] = make_float2(modL * cL, modL * sL);
  gamma[n] = expf(glog[n]);
}

// ---- scan phase 1: per-chunk local scan (zero init), emit chunk-final ---------------------
__global__ __launch_bounds__(256) void scan_partial(
    const short* __restrict__ re_h, const short* __restrict__ re_l,
    const short* __restrict__ im_h, const short* __restrict__ im_l,
    const float2* __restrict__ lam, float2* __restrict__ carry)
{
  const int g = blockIdx.x * 256 + threadIdx.x;
  const int n = g & (NST - 1);
  const int c = (g >> 9) & (NC - 1);
  const int b = g >> 14;
  const float2 L = lam[n];
  size_t idx = ((size_t)b * TLEN + (size_t)c * CL) * NST + n;
  float sr = 0.f, si = 0.f;
  #pragma unroll 4
  for (int t = 0; t < CL; ++t, idx += NST) {
    const float br = s2f(re_h[idx]) + s2f(re_l[idx]);
    const float bi = s2f(im_h[idx]) + s2f(im_l[idx]);
    const float nr = fmaf(L.x, sr, fmaf(-L.y, si, br));
    const float ni = fmaf(L.x, si, fmaf( L.y, sr, bi));
    sr = nr; si = ni;
  }
  carry[(size_t)(b * NC + c) * NST + n] = make_float2(sr, si);
}

// ---- scan phase 2: scan the 32 chunk summaries per (b,n); leaves carry-IN per chunk -------
__global__ __launch_bounds__(256) void scan_carry(
    float2* __restrict__ carry, const float2* __restrict__ lamL)
{
  const int g = blockIdx.x * 256 + threadIdx.x;   // 4096 threads
  const int n = g & (NST - 1);
  const int b = g >> 9;
  const float2 P = lamL[n];
  float sr = 0.f, si = 0.f;
  for (int c = 0; c < NC; ++c) {
    const size_t idx = (size_t)(b * NC + c) * NST + n;
    const float2 v = carry[idx];
    carry[idx] = make_float2(sr, si);
    const float nr = fmaf(P.x, sr, fmaf(-P.y, si, v.x));
    const float ni = fmaf(P.x, si, fmaf( P.y, sr, v.y));
    sr = nr; si = ni;
  }
}

// ---- scan phase 3: re-scan with carry-in, overwrite planes with state hi/lo ---------------
__global__ __launch_bounds__(256) void scan_final(
    short* __restrict__ re_h, short* __restrict__ re_l,
    short* __restrict__ im_h, short* __restrict__ im_l,
    const float2* __restrict__ lam, const float2* __restrict__ carry)
{
  const int g = blockIdx.x * 256 + threadIdx.x;
  const int n = g & (NST - 1);
  const int c = (g >> 9) & (NC - 1);
  const int b = g >> 14;
  const float2 L = lam[n];
  const float2 ci = carry[(size_t)(b * NC + c) * NST + n];
  size_t idx = ((size_t)b * TLEN + (size_t)c * CL) * NST + n;
  float sr = ci.x, si = ci.y;
  #pragma unroll 4
  for (int t = 0; t < CL; ++t, idx += NST) {
    const float br = s2f(re_h[idx]) + s2f(re_l[idx]);
    const float bi = s2f(im_h[idx]) + s2f(im_l[idx]);
    const float nr = fmaf(L.x, sr, fmaf(-L.y, si, br));
    const float ni = fmaf(L.x, si, fmaf( L.y, sr, bi));
    sr = nr; si = ni;
    short hh, ll;
    split(sr, hh, ll); re_h[idx] = hh; re_l[idx] = ll;
    split(si, hh, ll); im_h[idx] = hh; im_l[idx] = ll;
  }
}

// ---- kernel 5: y = st_re@Cre^T - st_im@Cim^T + x@D^T --------------------------------------
__global__ __launch_bounds__(256, 2) void out_mfma(
    const short* __restrict__ re_h, const short* __restrict__ re_l,
    const short* __restrict__ im_h, const short* __restrict__ im_l,
    const float* __restrict__ x,
    const float* __restrict__ Cre, const float* __restrict__ Cim,
    const float* __restrict__ Dm, float* __restrict__ y)
{
  __shared__ short Ah[128 * 32], Al[128 * 32], Bh[128 * 32], Bl[128 * 32];
  f32x4 acc[4][4] = {};
  const int tid = threadIdx.x;
  const int m0 = blockIdx.x * 128;
  const int o0 = blockIdx.y * 128;

  gemm_phase<true >(nullptr, re_h, re_l, NST, Cre, NST,  1.0f, NST, m0, o0, tid,
                    acc, Ah, Al, Bh, Bl);
  gemm_phase<true >(nullptr, im_h, im_l, NST, Cim, NST, -1.0f, NST, m0, o0, tid,
                    acc, Ah, Al, Bh, Bl);
  gemm_phase<false>(x, nullptr, nullptr, DIN, Dm, DIN, 1.0f, DIN, m0, o0, tid,
                    acc, Ah, Al, Bh, Bl);

  const int lane = tid & 63, w = tid >> 6, wm = w >> 1, wn = w & 1;
  const int lr = lane & 15, lq = lane >> 4;
  #pragma unroll
  for (int mi = 0; mi < 4; ++mi)
    #pragma unroll
    for (int j = 0; j < 4; ++j) {
      const size_t m = (size_t)m0 + wm * 64 + mi * 16 + lq * 4 + j;
      #pragma unroll
      for (int ni = 0; ni < 4; ++ni)
        y[m * DOUT + o0 + wn * 64 + ni * 16 + lr] = acc[mi][ni][j];
    }
}

// ---- host launch --------------------------------------------------------------------------
extern "C" void kernel_launch(void* const* d_in, const int* in_sizes, int n_in,
                              void* d_out, int out_size, void* d_ws, size_t ws_size,
                              hipStream_t stream)
{
  (void)in_sizes; (void)n_in; (void)out_size; (void)ws_size;
  const float* x     = (const float*)d_in[0];
  const float* nulog = (const float*)d_in[1];
  const float* thlog = (const float*)d_in[2];
  const float* glog  = (const float*)d_in[3];
  const float* Bre   = (const float*)d_in[4];
  const float* Bim   = (const float*)d_in[5];
  const float* Cre   = (const float*)d_in[6];
  const float* Cim   = (const float*)d_in[7];
  const float* Dm    = (const float*)d_in[8];
  float* y = (float*)d_out;

  // workspace layout (~135.3 MB): 4 bf16 planes | carry | lam | lamL | gamma
  const size_t PLANE = (size_t)M_TOT * NST;        // 16.78M shorts = 33.55 MB
  short*  re_h  = (short*)d_ws;
  short*  re_l  = re_h + PLANE;
  short*  im_h  = re_l + PLANE;
  short*  im_l  = im_h + PLANE;
  float2* carry = (float2*)(im_l + PLANE);
  float2* lam   = carry + (size_t)BSZ * NC * NST;
  float2* lamL  = lam + NST;
  float*  gamma = (float*)(lamL + NST);

  params_k<<<2, 256, 0, stream>>>(nulog, thlog, glog, lam, lamL, gamma);
  bu_mfma<<<dim3(M_TOT / 128, (2 * NST) / 128), 256, 0, stream>>>(
      x, Bre, Bim, gamma, re_h, re_l, im_h, im_l);
  scan_partial<<<(BSZ * NC * NST) / 256, 256, 0, stream>>>(re_h, re_l, im_h, im_l, lam, carry);
  scan_carry<<<(BSZ * NST) / 256, 256, 0, stream>>>(carry, lamL);
  scan_final<<<(BSZ * NC * NST) / 256, 256, 0, stream>>>(re_h, re_l, im_h, im_l, lam, carry);
  out_mfma<<<dim3(M_TOT / 128, DOUT / 128), 256, 0, stream>>>(
      re_h, re_l, im_h, im_l, x, Cre, Cim, Dm, y);
}

// Round 3
// 965.783 us; speedup vs baseline: 2.7266x; 1.0770x over previous
//
#include <hip/hip_runtime.h>

// LRU forward: y = Re(scan(lam, gamma*(x@B^T)) @ C^T) + x @ D^T
// Round 3: same bf16x3 split MFMA structure, LDS row stride padded 32->40 shorts (80B)
// to kill ds_write/ds_read bank conflicts (round-2 counter: 1.34e8 conflict cycles).

#define BSZ   8
#define TLEN  4096
#define DIN   1024
#define DOUT  1024
#define NST   512
#define M_TOT (BSZ * TLEN)   // 32768
#define NC    32             // scan chunks per sequence
#define CL    128            // chunk length; NC*CL == TLEN

#define LDR   40             // LDS row stride in shorts (80B = 5*16B -> bank-group bijective)

typedef __attribute__((ext_vector_type(8))) short bf16x8;   // MFMA A/B frag (4 VGPR)
typedef __attribute__((ext_vector_type(4))) float f32x4;    // MFMA C/D frag

// ---- bf16 helpers (bit-level, RNE) --------------------------------------------------------
__device__ __forceinline__ float s2f(short s) {
  unsigned v = ((unsigned)(unsigned short)s) << 16;
  return __builtin_bit_cast(float, v);
}
__device__ __forceinline__ short f2s(float f) {
  unsigned u = __builtin_bit_cast(unsigned, f);
  unsigned r = (u + 0x7FFFu + ((u >> 16) & 1u)) >> 16;
  return (short)r;
}
__device__ __forceinline__ void split(float f, short& h, short& l) {
  h = f2s(f);
  l = f2s(f - s2f(h));
}
__device__ __forceinline__ void split8(const float4 v0, const float4 v1, const float sgn,
                                       bf16x8& hv, bf16x8& lv) {
  const float f[8] = {v0.x, v0.y, v0.z, v0.w, v1.x, v1.y, v1.z, v1.w};
  #pragma unroll
  for (int j = 0; j < 8; ++j) { short hh, ll; split(sgn * f[j], hh, ll); hv[j] = hh; lv[j] = ll; }
}

// ---- MFMA compute for one staged K-step (BK=32) -------------------------------------------
__device__ __forceinline__ void mma_step(f32x4 (&acc)[4][4],
    const short* __restrict__ Ah, const short* __restrict__ Al,
    const short* __restrict__ Bh, const short* __restrict__ Bl,
    const int wm, const int wn, const int lane)
{
  const int lr = lane & 15, kg = lane >> 4;
  bf16x8 ah[4], al[4];
  #pragma unroll
  for (int mi = 0; mi < 4; ++mi) {
    const int ro = (wm * 64 + mi * 16 + lr) * LDR + kg * 8;
    ah[mi] = *(const bf16x8*)&Ah[ro];
    al[mi] = *(const bf16x8*)&Al[ro];
  }
  #pragma unroll
  for (int ni = 0; ni < 4; ++ni) {
    const int co = (wn * 64 + ni * 16 + lr) * LDR + kg * 8;
    const bf16x8 bh = *(const bf16x8*)&Bh[co];
    const bf16x8 bl = *(const bf16x8*)&Bl[co];
    #pragma unroll
    for (int mi = 0; mi < 4; ++mi) {
      acc[mi][ni] = __builtin_amdgcn_mfma_f32_16x16x32_bf16(ah[mi], bh, acc[mi][ni], 0, 0, 0);
      acc[mi][ni] = __builtin_amdgcn_mfma_f32_16x16x32_bf16(ah[mi], bl, acc[mi][ni], 0, 0, 0);
      acc[mi][ni] = __builtin_amdgcn_mfma_f32_16x16x32_bf16(al[mi], bh, acc[mi][ni], 0, 0, 0);
    }
  }
}

// ---- one GEMM phase: acc += Asrc[m0+..][K] * Bsrc[n0+..][K]^T (NT), split-bf16x3 ----------
// APLANES=1: A comes pre-split as two bf16 planes (row-major [*, lda]).
// APLANES=0: A is fp32, split on the fly. B is always fp32 (weights), sign folded in.
template<bool APLANES>
__device__ __forceinline__ void gemm_phase(
    const float* __restrict__ Af, const short* __restrict__ Aph, const short* __restrict__ Apl,
    const int lda,
    const float* __restrict__ Bf, const int ldb, const float bsgn,
    const int K, const int m0, const int n0, const int tid,
    f32x4 (&acc)[4][4], short* Ah, short* Al, short* Bh, short* Bl)
{
  const int r    = tid & 127;   // staged row (A: m-row, B: n-row)
  const int kh   = tid >> 7;    // which 16-wide half of the 32 k's
  const int lane = tid & 63, w = tid >> 6, wm = w >> 1, wn = w & 1;

  float4 pa[4], pb[4];
  bf16x8 ph0, ph1, pl0, pl1;

  if constexpr (APLANES) {
    const size_t off = (size_t)(m0 + r) * lda + kh * 16;
    ph0 = *(const bf16x8*)(Aph + off);  ph1 = *(const bf16x8*)(Aph + off + 8);
    pl0 = *(const bf16x8*)(Apl + off);  pl1 = *(const bf16x8*)(Apl + off + 8);
  } else {
    const float* p = Af + (size_t)(m0 + r) * lda + kh * 16;
    #pragma unroll
    for (int i = 0; i < 4; ++i) pa[i] = *(const float4*)(p + 4 * i);
  }
  {
    const float* p = Bf + (size_t)(n0 + r) * ldb + kh * 16;
    #pragma unroll
    for (int i = 0; i < 4; ++i) pb[i] = *(const float4*)(p + 4 * i);
  }

  for (int k0 = 0; k0 < K; k0 += 32) {
    __syncthreads();                       // prior K-step's LDS reads complete
    const int wo = r * LDR + kh * 16;
    if constexpr (APLANES) {
      *(bf16x8*)&Ah[wo] = ph0;  *(bf16x8*)&Ah[wo + 8] = ph1;
      *(bf16x8*)&Al[wo] = pl0;  *(bf16x8*)&Al[wo + 8] = pl1;
    } else {
      bf16x8 hv0, lv0, hv1, lv1;
      split8(pa[0], pa[1], 1.0f, hv0, lv0);
      split8(pa[2], pa[3], 1.0f, hv1, lv1);
      *(bf16x8*)&Ah[wo] = hv0;  *(bf16x8*)&Ah[wo + 8] = hv1;
      *(bf16x8*)&Al[wo] = lv0;  *(bf16x8*)&Al[wo + 8] = lv1;
    }
    {
      bf16x8 hv0, lv0, hv1, lv1;
      split8(pb[0], pb[1], bsgn, hv0, lv0);
      split8(pb[2], pb[3], bsgn, hv1, lv1);
      *(bf16x8*)&Bh[wo] = hv0;  *(bf16x8*)&Bh[wo + 8] = hv1;
      *(bf16x8*)&Bl[wo] = lv0;  *(bf16x8*)&Bl[wo + 8] = lv1;
    }
    __syncthreads();
    if (k0 + 32 < K) {                     // prefetch next K-tile, overlaps MFMA below
      if constexpr (APLANES) {
        const size_t off = (size_t)(m0 + r) * lda + (k0 + 32) + kh * 16;
        ph0 = *(const bf16x8*)(Aph + off);  ph1 = *(const bf16x8*)(Aph + off + 8);
        pl0 = *(const bf16x8*)(Apl + off);  pl1 = *(const bf16x8*)(Apl + off + 8);
      } else {
        const float* p = Af + (size_t)(m0 + r) * lda + (k0 + 32) + kh * 16;
        #pragma unroll
        for (int i = 0; i < 4; ++i) pa[i] = *(const float4*)(p + 4 * i);
      }
      const float* p = Bf + (size_t)(n0 + r) * ldb + (k0 + 32) + kh * 16;
      #pragma unroll
      for (int i = 0; i < 4; ++i) pb[i] = *(const float4*)(p + 4 * i);
    }
    mma_step(acc, Ah, Al, Bh, Bl, wm, wn, lane);
  }
}

// ---- kernel 1: Bu planes = split_bf16(gamma * (x @ [Bre|Bim]^T)) --------------------------
__global__ __launch_bounds__(256, 2) void bu_mfma(
    const float* __restrict__ x, const float* __restrict__ Bre, const float* __restrict__ Bim,
    const float* __restrict__ gamma,
    short* __restrict__ re_h, short* __restrict__ re_l,
    short* __restrict__ im_h, short* __restrict__ im_l)
{
  __shared__ short Ah[128 * LDR], Al[128 * LDR], Bh[128 * LDR], Bl[128 * LDR];
  f32x4 acc[4][4] = {};
  const int tid = threadIdx.x;
  const int m0  = blockIdx.x * 128;
  const int n0s = blockIdx.y * 128;                  // stacked col 0..1023
  const float* Bsel = (n0s < NST) ? Bre : Bim;
  const int nb0 = n0s & (NST - 1);

  gemm_phase<false>(x, nullptr, nullptr, DIN, Bsel, DIN, 1.0f, DIN, m0, nb0, tid,
                    acc, Ah, Al, Bh, Bl);

  short* Hp = (n0s < NST) ? re_h : im_h;
  short* Lp = (n0s < NST) ? re_l : im_l;
  const int lane = tid & 63, w = tid >> 6, wm = w >> 1, wn = w & 1;
  const int lr = lane & 15, lq = lane >> 4;
  #pragma unroll
  for (int ni = 0; ni < 4; ++ni) {
    const int nb = nb0 + wn * 64 + ni * 16 + lr;
    const float g = gamma[nb];
    #pragma unroll
    for (int mi = 0; mi < 4; ++mi)
      #pragma unroll
      for (int j = 0; j < 4; ++j) {
        const size_t m = (size_t)m0 + wm * 64 + mi * 16 + lq * 4 + j;
        short hh, ll;
        split(acc[mi][ni][j] * g, hh, ll);
        Hp[m * NST + nb] = hh;
        Lp[m * NST + nb] = ll;
      }
  }
}

// ---- scan params --------------------------------------------------------------------------
__global__ void params_k(const float* __restrict__ nulog, const float* __restrict__ thlog,
                         const float* __restrict__ glog,
                         float2* __restrict__ lam, float2* __restrict__ lamL,
                         float* __restrict__ gamma)
{
  const int n = blockIdx.x * 256 + threadIdx.x;
  if (n >= NST) return;
  const float nu = expf(nulog[n]);
  const float th = expf(thlog[n]);
  const float mod = expf(-nu);
  float s, c;
  sincosf(th, &s, &c);
  lam[n] = make_float2(mod * c, mod * s);
  const float modL = expf(-(float)CL * nu);
  float sL, cL;
  sincosf((float)CL * th, &sL, &cL);
  lamL[n] = make_float2(modL * cL, modL * sL);
  gamma[n] = expf(glog[n]);
}

// ---- scan phase 1: per-chunk local scan (zero init), emit chunk-final ---------------------
__global__ __launch_bounds__(256) void scan_partial(
    const short* __restrict__ re_h, const short* __restrict__ re_l,
    const short* __restrict__ im_h, const short* __restrict__ im_l,
    const float2* __restrict__ lam, float2* __restrict__ carry)
{
  const int g = blockIdx.x * 256 + threadIdx.x;
  const int n = g & (NST - 1);
  const int c = (g >> 9) & (NC - 1);
  const int b = g >> 14;
  const float2 L = lam[n];
  size_t idx = ((size_t)b * TLEN + (size_t)c * CL) * NST + n;
  float sr = 0.f, si = 0.f;
  #pragma unroll 4
  for (int t = 0; t < CL; ++t, idx += NST) {
    const float br = s2f(re_h[idx]) + s2f(re_l[idx]);
    const float bi = s2f(im_h[idx]) + s2f(im_l[idx]);
    const float nr = fmaf(L.x, sr, fmaf(-L.y, si, br));
    const float ni = fmaf(L.x, si, fmaf( L.y, sr, bi));
    sr = nr; si = ni;
  }
  carry[(size_t)(b * NC + c) * NST + n] = make_float2(sr, si);
}

// ---- scan phase 2: scan the 32 chunk summaries per (b,n); leaves carry-IN per chunk -------
__global__ __launch_bounds__(256) void scan_carry(
    float2* __restrict__ carry, const float2* __restrict__ lamL)
{
  const int g = blockIdx.x * 256 + threadIdx.x;   // 4096 threads
  const int n = g & (NST - 1);
  const int b = g >> 9;
  const float2 P = lamL[n];
  float sr = 0.f, si = 0.f;
  for (int c = 0; c < NC; ++c) {
    const size_t idx = (size_t)(b * NC + c) * NST + n;
    const float2 v = carry[idx];
    carry[idx] = make_float2(sr, si);
    const float nr = fmaf(P.x, sr, fmaf(-P.y, si, v.x));
    const float ni = fmaf(P.x, si, fmaf( P.y, sr, v.y));
    sr = nr; si = ni;
  }
}

// ---- scan phase 3: re-scan with carry-in, overwrite planes with state hi/lo ---------------
__global__ __launch_bounds__(256) void scan_final(
    short* __restrict__ re_h, short* __restrict__ re_l,
    short* __restrict__ im_h, short* __restrict__ im_l,
    const float2* __restrict__ lam, const float2* __restrict__ carry)
{
  const int g = blockIdx.x * 256 + threadIdx.x;
  const int n = g & (NST - 1);
  const int c = (g >> 9) & (NC - 1);
  const int b = g >> 14;
  const float2 L = lam[n];
  const float2 ci = carry[(size_t)(b * NC + c) * NST + n];
  size_t idx = ((size_t)b * TLEN + (size_t)c * CL) * NST + n;
  float sr = ci.x, si = ci.y;
  #pragma unroll 4
  for (int t = 0; t < CL; ++t, idx += NST) {
    const float br = s2f(re_h[idx]) + s2f(re_l[idx]);
    const float bi = s2f(im_h[idx]) + s2f(im_l[idx]);
    const float nr = fmaf(L.x, sr, fmaf(-L.y, si, br));
    const float ni = fmaf(L.x, si, fmaf( L.y, sr, bi));
    sr = nr; si = ni;
    short hh, ll;
    split(sr, hh, ll); re_h[idx] = hh; re_l[idx] = ll;
    split(si, hh, ll); im_h[idx] = hh; im_l[idx] = ll;
  }
}

// ---- kernel 5: y = st_re@Cre^T - st_im@Cim^T + x@D^T --------------------------------------
__global__ __launch_bounds__(256, 2) void out_mfma(
    const short* __restrict__ re_h, const short* __restrict__ re_l,
    const short* __restrict__ im_h, const short* __restrict__ im_l,
    const float* __restrict__ x,
    const float* __restrict__ Cre, const float* __restrict__ Cim,
    const float* __restrict__ Dm, float* __restrict__ y)
{
  __shared__ short Ah[128 * LDR], Al[128 * LDR], Bh[128 * LDR], Bl[128 * LDR];
  f32x4 acc[4][4] = {};
  const int tid = threadIdx.x;
  const int m0 = blockIdx.x * 128;
  const int o0 = blockIdx.y * 128;

  gemm_phase<true >(nullptr, re_h, re_l, NST, Cre, NST,  1.0f, NST, m0, o0, tid,
                    acc, Ah, Al, Bh, Bl);
  gemm_phase<true >(nullptr, im_h, im_l, NST, Cim, NST, -1.0f, NST, m0, o0, tid,
                    acc, Ah, Al, Bh, Bl);
  gemm_phase<false>(x, nullptr, nullptr, DIN, Dm, DIN, 1.0f, DIN, m0, o0, tid,
                    acc, Ah, Al, Bh, Bl);

  const int lane = tid & 63, w = tid >> 6, wm = w >> 1, wn = w & 1;
  const int lr = lane & 15, lq = lane >> 4;
  #pragma unroll
  for (int mi = 0; mi < 4; ++mi)
    #pragma unroll
    for (int j = 0; j < 4; ++j) {
      const size_t m = (size_t)m0 + wm * 64 + mi * 16 + lq * 4 + j;
      #pragma unroll
      for (int ni = 0; ni < 4; ++ni)
        y[m * DOUT + o0 + wn * 64 + ni * 16 + lr] = acc[mi][ni][j];
    }
}

// ---- host launch --------------------------------------------------------------------------
extern "C" void kernel_launch(void* const* d_in, const int* in_sizes, int n_in,
                              void* d_out, int out_size, void* d_ws, size_t ws_size,
                              hipStream_t stream)
{
  (void)in_sizes; (void)n_in; (void)out_size; (void)ws_size;
  const float* x     = (const float*)d_in[0];
  const float* nulog = (const float*)d_in[1];
  const float* thlog = (const float*)d_in[2];
  const float* glog  = (const float*)d_in[3];
  const float* Bre   = (const float*)d_in[4];
  const float* Bim   = (const float*)d_in[5];
  const float* Cre   = (const float*)d_in[6];
  const float* Cim   = (const float*)d_in[7];
  const float* Dm    = (const float*)d_in[8];
  float* y = (float*)d_out;

  // workspace layout (~135.3 MB): 4 bf16 planes | carry | lam | lamL | gamma
  const size_t PLANE = (size_t)M_TOT * NST;        // 16.78M shorts = 33.55 MB
  short*  re_h  = (short*)d_ws;
  short*  re_l  = re_h + PLANE;
  short*  im_h  = re_l + PLANE;
  short*  im_l  = im_h + PLANE;
  float2* carry = (float2*)(im_l + PLANE);
  float2* lam   = carry + (size_t)BSZ * NC * NST;
  float2* lamL  = lam + NST;
  float*  gamma = (float*)(lamL + NST);

  params_k<<<2, 256, 0, stream>>>(nulog, thlog, glog, lam, lamL, gamma);
  bu_mfma<<<dim3(M_TOT / 128, (2 * NST) / 128), 256, 0, stream>>>(
      x, Bre, Bim, gamma, re_h, re_l, im_h, im_l);
  scan_partial<<<(BSZ * NC * NST) / 256, 256, 0, stream>>>(re_h, re_l, im_h, im_l, lam, carry);
  scan_carry<<<(BSZ * NST) / 256, 256, 0, stream>>>(carry, lamL);
  scan_final<<<(BSZ * NC * NST) / 256, 256, 0, stream>>>(re_h, re_l, im_h, im_l, lam, carry);
  out_mfma<<<dim3(M_TOT / 128, DOUT / 128), 256, 0, stream>>>(
      re_h, re_l, im_h, im_l, x, Cre, Cim, Dm, y);
}